// Round 7
// baseline (338.467 us; speedup 1.0000x reference)
//
#include <hip/hip_runtime.h>

// InterpretableMultiHeadAttention: B=8,S=1024,H=1024,NH=16,D=64,V=1024
// out = (mean_n softmax(causal(qh_n kh_n^T / 8))) @ (v Wv + bv)
// Round 7: stats & pbar rewritten LDS-free/barrier-free — Q frags in regs,
// K fragments streamed global->VGPR (one 128B line per K row, L1-served
// across the block's 4 waves). Exact per-wave causal tile counts.

#define NHEAD 16
#define BATCH 8
#define SEQ   1024
#define HID   1024
#define DHEAD 64

typedef _Float16 f16;
typedef _Float16 f16x4 __attribute__((ext_vector_type(4)));
typedef _Float16 f16x8 __attribute__((ext_vector_type(8)));
typedef float    f32x4 __attribute__((ext_vector_type(4)));

__device__ __forceinline__ f32x4 mfma16(f16x8 a, f16x8 b, f32x4 c) {
  return __builtin_amdgcn_mfma_f32_16x16x32_f16(a, b, c, 0, 0, 0);
}

__device__ __forceinline__ void gload16(const f16* g, f16* l) {
  __builtin_amdgcn_global_load_lds(
      (const __attribute__((address_space(1))) void*)g,
      (__attribute__((address_space(3))) void*)l, 16, 0, 0);
}

// GEMM staging (unchanged, verified conflict-free).
__device__ __forceinline__ void stage_swz(const f16* __restrict__ g, int ldg,
                                          f16* lds, int nch, int tid) {
  for (int idx = tid; idx < nch; idx += 256) {
    int row = idx >> 3, c16 = idx & 7;
    int sc = c16 ^ (row & 7);
    gload16(g + (size_t)row * ldg + sc * 8, lds + (size_t)(idx & ~63) * 8);
  }
}

__device__ __forceinline__ f16x8 lds_frag(const f16* lds, int row, int c16) {
  int sc = c16 ^ (row & 7);
  return *(const f16x8*)&lds[row * 64 + sc * 8];
}

// ---------------- conversions ----------------

__global__ __launch_bounds__(256) void conv3(
    const float* __restrict__ q, const float* __restrict__ k,
    const float* __restrict__ v, f16* __restrict__ dq, f16* __restrict__ dk,
    f16* __restrict__ dv) {
  const float* src = blockIdx.z == 0 ? q : blockIdx.z == 1 ? k : v;
  f16* dst = blockIdx.z == 0 ? dq : blockIdx.z == 1 ? dk : dv;
  int i = (blockIdx.x * 256 + threadIdx.x) * 4;
  float4 f = *(const float4*)(src + i);
  f16x4 o = { (f16)f.x, (f16)f.y, (f16)f.z, (f16)f.w };
  *(f16x4*)(dst + i) = o;
}

__global__ __launch_bounds__(256) void tconv2(
    const float* __restrict__ s0, const float* __restrict__ s1,
    f16* __restrict__ d0, f16* __restrict__ d1, int R, int C, int half) {
  int z = blockIdx.z;
  const float* src; f16* dst;
  if (z < half) { src = s0 + (size_t)z * R * C; dst = d0 + (size_t)z * R * C; }
  else { src = s1 + (size_t)(z - half) * R * C; dst = d1 + (size_t)(z - half) * R * C; }
  const int c0 = blockIdx.x * 64, r0 = blockIdx.y * 64;
  __shared__ f16 t[64][72];
  const int tid = threadIdx.x;
#pragma unroll
  for (int i = 0; i < 4; i++) {
    int chunk = tid + i * 256;
    int row = chunk >> 4, c4 = chunk & 15;
    float4 f = *(const float4*)&src[(size_t)(r0 + row) * C + c0 + c4 * 4];
    f16x4 h = { (f16)f.x, (f16)f.y, (f16)f.z, (f16)f.w };
    *(f16x4*)&t[row][c4 * 4] = h;
  }
  __syncthreads();
  const int cc = tid >> 2, q = tid & 3;
  f16 tmp[16];
#pragma unroll
  for (int j = 0; j < 16; j++) tmp[j] = t[q * 16 + j][cc];
  *(f16x8*)&dst[(size_t)(c0 + cc) * R + r0 + q * 16] = *(f16x8*)&tmp[0];
  *(f16x8*)&dst[(size_t)(c0 + cc) * R + r0 + q * 16 + 8] = *(f16x8*)&tmp[8];
}

// ---------------- shared GEMM core: 128x128 tile, BK=64, 4 waves ----------------

__device__ __forceinline__ void gemm_core(
    const f16* __restrict__ A, const f16* __restrict__ Bt, int K, int Kend,
    int row0, int col0, f16* la, f16* lb, int tid, f32x4 (&acc)[4][4]) {
  const int lane = tid & 63;
  const int wr = (tid >> 6) >> 1, wc = (tid >> 6) & 1;
  for (int k0 = 0; k0 < Kend; k0 += 64) {
    __syncthreads();
    stage_swz(A + (size_t)row0 * K + k0, K, la, 1024, tid);
    stage_swz(Bt + (size_t)col0 * K + k0, K, lb, 1024, tid);
    __syncthreads();
#pragma unroll
    for (int ks = 0; ks < 2; ks++) {
      f16x8 af[4], bfr[4];
#pragma unroll
      for (int mi = 0; mi < 4; mi++)
        af[mi] = lds_frag(la, wr * 64 + mi * 16 + (lane & 15), ks * 4 + (lane >> 4));
#pragma unroll
      for (int ni = 0; ni < 4; ni++)
        bfr[ni] = lds_frag(lb, wc * 64 + ni * 16 + (lane & 15), ks * 4 + (lane >> 4));
#pragma unroll
      for (int mi = 0; mi < 4; mi++)
#pragma unroll
        for (int ni = 0; ni < 4; ni++)
          acc[mi][ni] = mfma16(af[mi], bfr[ni], acc[mi][ni]);
    }
  }
}

// ---------------- projection GEMM (q & k batched via z) ----------------

__global__ __launch_bounds__(256) void proj_gemm(
    const f16* __restrict__ A0, const f16* __restrict__ A1,
    const f16* __restrict__ Bt0, const f16* __restrict__ Bt1,
    const float* __restrict__ bias0, const float* __restrict__ bias1,
    f16* __restrict__ C0, f16* __restrict__ C1) {
  const int which = blockIdx.z;
  const f16* A = which ? A1 : A0;
  const f16* Bt = which ? Bt1 : Bt0;
  const float* bias = which ? bias1 : bias0;
  f16* C = which ? C1 : C0;
  __shared__ alignas(16) f16 la[128 * 64];
  __shared__ alignas(16) f16 lb[128 * 64];
  const int tid = threadIdx.x, lane = tid & 63;
  const int wr = (tid >> 6) >> 1, wc = (tid >> 6) & 1;
  const int row0 = blockIdx.x * 128, col0 = blockIdx.y * 128;
  f32x4 acc[4][4];
#pragma unroll
  for (int i = 0; i < 4; i++)
#pragma unroll
    for (int j = 0; j < 4; j++) acc[i][j] = (f32x4){0.f, 0.f, 0.f, 0.f};
  gemm_core(A, Bt, HID, HID, row0, col0, la, lb, tid, acc);
#pragma unroll
  for (int mi = 0; mi < 4; mi++)
#pragma unroll
    for (int ni = 0; ni < 4; ni++)
#pragma unroll
      for (int r = 0; r < 4; r++) {
        int m = row0 + wr * 64 + mi * 16 + ((lane >> 4) << 2) + r;
        int j = col0 + wc * 64 + ni * 16 + (lane & 15);
        float val = acc[mi][ni][r] + bias[j];
        int bb = m >> 10, s = m & 1023, hn = j >> 6, d = j & 63;
        C[(((size_t)hn * BATCH + bb) * SEQ + s) * DHEAD + d] = (f16)val;
      }
}

// ---------------- vv GEMM: vvT[b][v][t] = WvT x v^T + bv[row] ----------------

__global__ __launch_bounds__(256) void vv_gemm(
    const f16* __restrict__ A, const f16* __restrict__ Bt,
    const float* __restrict__ bias, f16* __restrict__ C) {
  __shared__ alignas(16) f16 la[128 * 64];
  __shared__ alignas(16) f16 lb[128 * 64];
  const int tid = threadIdx.x, lane = tid & 63;
  const int wr = (tid >> 6) >> 1, wc = (tid >> 6) & 1;
  const int row0 = blockIdx.x * 128, col0 = blockIdx.y * 128;
  f32x4 acc[4][4];
#pragma unroll
  for (int i = 0; i < 4; i++)
#pragma unroll
    for (int j = 0; j < 4; j++) acc[i][j] = (f32x4){0.f, 0.f, 0.f, 0.f};
  gemm_core(A, Bt, HID, HID, row0, col0, la, lb, tid, acc);
#pragma unroll
  for (int mi = 0; mi < 4; mi++)
#pragma unroll
    for (int ni = 0; ni < 4; ni++)
#pragma unroll
      for (int r = 0; r < 4; r++) {
        int m = row0 + wr * 64 + mi * 16 + ((lane >> 4) << 2) + r;
        int j = col0 + wc * 64 + ni * 16 + (lane & 15);
        float val = acc[mi][ni][r] + bias[m];
        int bb = j >> 10, t = j & 1023;
        C[((size_t)bb * SEQ + m) * SEQ + t] = (f16)val;
      }
}

// ---------------- attention pass 1: LDS-free row sums ----------------
// grid (16 sb longest-first, 8 b, 16 n), 4 waves x 16 rows. Each wave:
// Q frags in regs, K frags streamed global->VGPR. nf full k-tiles + 1 masked.

__global__ __launch_bounds__(256) void attn_stats(
    const f16* __restrict__ QH, const f16* __restrict__ KH,
    float* __restrict__ madj_ws) {
  const int sb = 15 - blockIdx.x;
  const int b = blockIdx.y, n = blockIdx.z;
  const int s0 = sb * 64;
  const f16* qh = QH + ((size_t)n * BATCH + b) * SEQ * DHEAD;
  const f16* kh = KH + ((size_t)n * BATCH + b) * SEQ * DHEAD;

  const int tid = threadIdx.x, lane = tid & 63, wave = tid >> 6;
  const int qrow = s0 + wave * 16 + (lane & 15);
  const int ch = (lane >> 4) << 3;  // 0,8,16,24

  f16x8 aq0 = *(const f16x8*)&qh[(size_t)qrow * 64 + ch];
  f16x8 aq1 = *(const f16x8*)&qh[(size_t)qrow * 64 + 32 + ch];

  const float sl2e = 0.125f * 1.44269504088896f;
  float l_p[4] = {0.f, 0.f, 0.f, 0.f};
  const int srow = s0 + wave * 16 + ((lane >> 4) << 2);
  const int nf = (s0 >> 4) + wave;  // full (unmasked) 16-row k-tiles

  const f16* kp = kh + (size_t)(lane & 15) * 64 + ch;
  int t = 0;
  for (; t + 2 <= nf; t += 2) {
    const f16* p = kp + (size_t)t * 1024;
    f16x8 b0a = *(const f16x8*)(p);
    f16x8 b1a = *(const f16x8*)(p + 32);
    f16x8 b0b = *(const f16x8*)(p + 1024);
    f16x8 b1b = *(const f16x8*)(p + 1024 + 32);
    f32x4 ca = (f32x4){0.f, 0.f, 0.f, 0.f};
    f32x4 cb = (f32x4){0.f, 0.f, 0.f, 0.f};
    ca = mfma16(aq0, b0a, ca); ca = mfma16(aq1, b1a, ca);
    cb = mfma16(aq0, b0b, cb); cb = mfma16(aq1, b1b, cb);
#pragma unroll
    for (int r = 0; r < 4; r++)
      l_p[r] += exp2f(ca[r] * sl2e) + exp2f(cb[r] * sl2e);
  }
  if (t < nf) {
    const f16* p = kp + (size_t)t * 1024;
    f16x8 b0 = *(const f16x8*)(p);
    f16x8 b1 = *(const f16x8*)(p + 32);
    f32x4 c = (f32x4){0.f, 0.f, 0.f, 0.f};
    c = mfma16(aq0, b0, c); c = mfma16(aq1, b1, c);
#pragma unroll
    for (int r = 0; r < 4; r++) l_p[r] += exp2f(c[r] * sl2e);
    t++;
  }
  {  // diagonal (masked) tile: k in [s0+wave*16, s0+wave*16+16)
    const f16* p = kp + (size_t)nf * 1024;
    f16x8 b0 = *(const f16x8*)(p);
    f16x8 b1 = *(const f16x8*)(p + 32);
    f32x4 c = (f32x4){0.f, 0.f, 0.f, 0.f};
    c = mfma16(aq0, b0, c); c = mfma16(aq1, b1, c);
    int tg = (nf << 4) + (lane & 15);
#pragma unroll
    for (int r = 0; r < 4; r++)
      l_p[r] += (tg <= srow + r) ? exp2f(c[r] * sl2e) : 0.f;
  }

#pragma unroll
  for (int r = 0; r < 4; r++) {
    float l = l_p[r];
#pragma unroll
    for (int off = 1; off < 16; off <<= 1) l += __shfl_xor(l, off);
    if ((lane & 15) == 0) {
      size_t base = ((size_t)n * BATCH + b) * SEQ;
      madj_ws[base + srow + r] = -__log2f(l) - 4.0f;  // folds 1/l and /16
    }
  }
}

// ---------------- attention pass 2: LDS-free pbar partials ----------------
// grid (72 active (sb,tc128) flat longest-first, 16 = b*2+g). 8 heads/wave,
// Q/K direct from global, pacc[8][4] in VGPRs, per-wave exact tile count.

__global__ __launch_bounds__(256) void attn_pbar(
    const f16* __restrict__ QH, const f16* __restrict__ KH,
    const float* __restrict__ madj_ws, f16* __restrict__ pp) {
  int f = blockIdx.x, sb = 0, tcid = 0;
  for (int s = 15; s >= 0; --s) {       // longest-first decode
    int c = (s >> 1) + 1;
    if (f < c) { sb = s; tcid = f; break; }
    f -= c;
  }
  const int s0 = sb * 64, t0 = tcid * 128;
  const int b = blockIdx.y >> 1, g = blockIdx.y & 1;
  const int n0 = g * 8;

  const int tid = threadIdx.x, lane = tid & 63, wave = tid >> 6;
  const float sl2e = 0.125f * 1.44269504088896f;
  const int ch = (lane >> 4) << 3;
  const int qrow = s0 + wave * 16 + (lane & 15);
  const int srow = s0 + wave * 16 + ((lane >> 4) << 2);
  const int wmin = s0 + wave * 16;            // wave's min row
  // tiles to compute: t0+tc*16 <= wmin+15
  int ntc = ((wmin + 15 - t0) >> 4) + 1;
  ntc = ntc < 0 ? 0 : (ntc > 8 ? 8 : ntc);

  float pacc[8][4];
#pragma unroll
  for (int tc = 0; tc < 8; tc++)
#pragma unroll
    for (int r = 0; r < 4; r++) pacc[tc][r] = 0.f;

  for (int nn = 0; nn < 8; nn++) {
    const int n = n0 + nn;
    const f16* qh = QH + ((size_t)n * BATCH + b) * SEQ * DHEAD;
    const f16* kh = KH + ((size_t)n * BATCH + b) * SEQ * DHEAD;
    f16x8 aq0 = *(const f16x8*)&qh[(size_t)qrow * 64 + ch];
    f16x8 aq1 = *(const f16x8*)&qh[(size_t)qrow * 64 + 32 + ch];
    float4 ma = *(const float4*)&madj_ws[((size_t)n * BATCH + b) * SEQ + srow];
    float madj[4] = {ma.x, ma.y, ma.z, ma.w};
    const f16* kp = kh + (size_t)(t0 + (lane & 15)) * 64 + ch;

#pragma unroll
    for (int tc = 0; tc < 8; tc++) {
      if (tc < ntc) {
        const f16* p = kp + (size_t)tc * 1024;
        f16x8 b0 = *(const f16x8*)(p);
        f16x8 b1 = *(const f16x8*)(p + 32);
        f32x4 c = (f32x4){0.f, 0.f, 0.f, 0.f};
        c = mfma16(aq0, b0, c);
        c = mfma16(aq1, b1, c);
        int tg = t0 + tc * 16 + (lane & 15);
        bool edge = (t0 + tc * 16 + 15) > wmin;
#pragma unroll
        for (int r = 0; r < 4; r++) {
          float p2 = exp2f(fmaf(c[r], sl2e, madj[r]));
          if (edge) p2 = (tg <= srow + r) ? p2 : 0.f;
          pacc[tc][r] += p2;
        }
      }
    }
  }

  f16* out = pp + ((size_t)g * BATCH + b) * SEQ * SEQ;
#pragma unroll
  for (int tc = 0; tc < 8; tc++) {
    int tg = t0 + tc * 16 + (lane & 15);
#pragma unroll
    for (int r = 0; r < 4; r++)
      out[(size_t)(srow + r) * SEQ + tg] = (f16)pacc[tc][r];
  }
}

// ---------------- PV: out[b] = (pp0[b] + pp1[b]) @ vv[b], causal K-limit ----

__global__ __launch_bounds__(256) void pv_gemm(
    const f16* __restrict__ pp, const f16* __restrict__ vvT,
    float* __restrict__ out) {
  const int b = blockIdx.z;
  const size_t GS = (size_t)BATCH * SEQ * SEQ;
  const f16* A0 = pp + (size_t)b * SEQ * SEQ;
  const f16* A1 = pp + GS + (size_t)b * SEQ * SEQ;
  const f16* Bt = vvT + (size_t)b * SEQ * SEQ;
  __shared__ alignas(16) f16 la0[128 * 64];
  __shared__ alignas(16) f16 la1[128 * 64];
  __shared__ alignas(16) f16 lb[128 * 64];
  const int tid = threadIdx.x, lane = tid & 63;
  const int wr = (tid >> 6) >> 1, wc = (tid >> 6) & 1;
  const int row0 = blockIdx.x * 128, col0 = blockIdx.y * 128;
  const int Kend = (row0 + 128 < SEQ) ? row0 + 128 : SEQ;

  f32x4 acc[4][4];
#pragma unroll
  for (int i = 0; i < 4; i++)
#pragma unroll
    for (int j = 0; j < 4; j++) acc[i][j] = (f32x4){0.f, 0.f, 0.f, 0.f};

  for (int k0 = 0; k0 < Kend; k0 += 64) {
    __syncthreads();
    stage_swz(A0 + (size_t)row0 * SEQ + k0, SEQ, la0, 1024, tid);
    stage_swz(A1 + (size_t)row0 * SEQ + k0, SEQ, la1, 1024, tid);
    stage_swz(Bt + (size_t)col0 * SEQ + k0, SEQ, lb, 1024, tid);
    __syncthreads();
#pragma unroll
    for (int ks = 0; ks < 2; ks++) {
      f16x8 a0[4], a1[4], bfr[4];
#pragma unroll
      for (int mi = 0; mi < 4; mi++) {
        a0[mi] = lds_frag(la0, wr * 64 + mi * 16 + (lane & 15), ks * 4 + (lane >> 4));
        a1[mi] = lds_frag(la1, wr * 64 + mi * 16 + (lane & 15), ks * 4 + (lane >> 4));
      }
#pragma unroll
      for (int ni = 0; ni < 4; ni++)
        bfr[ni] = lds_frag(lb, wc * 64 + ni * 16 + (lane & 15), ks * 4 + (lane >> 4));
#pragma unroll
      for (int mi = 0; mi < 4; mi++)
#pragma unroll
        for (int ni = 0; ni < 4; ni++) {
          acc[mi][ni] = mfma16(a0[mi], bfr[ni], acc[mi][ni]);
          acc[mi][ni] = mfma16(a1[mi], bfr[ni], acc[mi][ni]);
        }
    }
  }

#pragma unroll
  for (int mi = 0; mi < 4; mi++)
#pragma unroll
    for (int ni = 0; ni < 4; ni++)
#pragma unroll
      for (int r = 0; r < 4; r++) {
        int m = row0 + wr * 64 + mi * 16 + ((lane >> 4) << 2) + r;
        int j = col0 + wc * 64 + ni * 16 + (lane & 15);
        out[(size_t)b * SEQ * SEQ + (size_t)m * SEQ + j] = acc[mi][ni][r];
      }
}

// ---------------- launcher ----------------

extern "C" void kernel_launch(void* const* d_in, const int* in_sizes, int n_in,
                              void* d_out, int out_size, void* d_ws, size_t ws_size,
                              hipStream_t stream) {
  (void)in_sizes; (void)n_in; (void)out_size; (void)ws_size;
  const float* q  = (const float*)d_in[0];
  const float* k  = (const float*)d_in[1];
  const float* v  = (const float*)d_in[2];
  const float* Wq = (const float*)d_in[3];
  const float* bq = (const float*)d_in[4];
  const float* Wk = (const float*)d_in[5];
  const float* bk = (const float*)d_in[6];
  const float* Wv = (const float*)d_in[7];
  const float* bv = (const float*)d_in[8];
  float* out = (float*)d_out;

  const size_t EL  = (size_t)BATCH * SEQ * HID;      // 8388608
  const size_t WEL = (size_t)NHEAD * HID * DHEAD;    // 1048576

  char* ws = (char*)d_ws;
  f16* qbf = (f16*)ws;  ws += EL * 2;
  f16* kbf = (f16*)ws;  ws += EL * 2;
  f16* vbf = (f16*)ws;  ws += EL * 2;
  f16* WqT = (f16*)ws;  ws += WEL * 2;
  f16* WkT = (f16*)ws;  ws += WEL * 2;
  f16* WvT = (f16*)ws;  ws += WEL * 2;
  f16* QHb = (f16*)ws;  ws += EL * 2;   // [n][b][s][d]
  f16* KHb = (f16*)ws;  ws += EL * 2;   // [n][b][t][d]
  f16* vvT = (f16*)ws;  ws += EL * 2;   // [b][v][t]
  float* madj_ws = (float*)ws; ws += (size_t)NHEAD * BATCH * SEQ * 4;
  // pp[2][b][s][t] f16 overlays qbf+kbf (dead after proj GEMMs)
  f16* pp = qbf;

  conv3<<<dim3(8192, 1, 3), 256, 0, stream>>>(q, k, v, qbf, kbf, vbf);
  tconv2<<<dim3(1, 16, 32), 256, 0, stream>>>(Wq, Wk, WqT, WkT, 1024, 64, 16);
  tconv2<<<dim3(16, 16, 1), 256, 0, stream>>>(Wv, Wv, WvT, WvT, 1024, 1024, 1);

  proj_gemm<<<dim3(64, 8, 2), 256, 0, stream>>>(qbf, kbf, WqT, WkT, bq, bk,
                                                QHb, KHb);
  vv_gemm<<<dim3(8, 64, 1), 256, 0, stream>>>(WvT, vbf, bv, vvT);

  attn_stats<<<dim3(16, 8, 16), 256, 0, stream>>>(QHb, KHb, madj_ws);
  attn_pbar<<<dim3(72, 16, 1), 256, 0, stream>>>(QHb, KHb, madj_ws, pp);
  pv_gemm<<<dim3(8, 8, 8), 256, 0, stream>>>(pp, vvT, out);
}

// Round 8
// 314.005 us; speedup vs baseline: 1.0779x; 1.0779x over previous
//
#include <hip/hip_runtime.h>

// InterpretableMultiHeadAttention: B=8,S=1024,H=1024,NH=16,D=64,V=1024
// out = (mean_n softmax(causal(qh_n kh_n^T / 8))) @ (v Wv + bv)
// Round 8: stats & pbar LDS-free with register double-buffered GROUP
// pipelining (4 tiles = 8 loads in flight while computing previous group);
// pbar pipelines across heads with Q/madj prefetch; XCD-swizzled flat grids.

#define NHEAD 16
#define BATCH 8
#define SEQ   1024
#define HID   1024
#define DHEAD 64

typedef _Float16 f16;
typedef _Float16 f16x4 __attribute__((ext_vector_type(4)));
typedef _Float16 f16x8 __attribute__((ext_vector_type(8)));
typedef float    f32x4 __attribute__((ext_vector_type(4)));

__device__ __forceinline__ f32x4 mfma16(f16x8 a, f16x8 b, f32x4 c) {
  return __builtin_amdgcn_mfma_f32_16x16x32_f16(a, b, c, 0, 0, 0);
}

__device__ __forceinline__ void gload16(const f16* g, f16* l) {
  __builtin_amdgcn_global_load_lds(
      (const __attribute__((address_space(1))) void*)g,
      (__attribute__((address_space(3))) void*)l, 16, 0, 0);
}

// GEMM staging (verified conflict-free).
__device__ __forceinline__ void stage_swz(const f16* __restrict__ g, int ldg,
                                          f16* lds, int nch, int tid) {
  for (int idx = tid; idx < nch; idx += 256) {
    int row = idx >> 3, c16 = idx & 7;
    int sc = c16 ^ (row & 7);
    gload16(g + (size_t)row * ldg + sc * 8, lds + (size_t)(idx & ~63) * 8);
  }
}

__device__ __forceinline__ f16x8 lds_frag(const f16* lds, int row, int c16) {
  int sc = c16 ^ (row & 7);
  return *(const f16x8*)&lds[row * 64 + sc * 8];
}

// ---------------- conversions ----------------

__global__ __launch_bounds__(256) void conv3(
    const float* __restrict__ q, const float* __restrict__ k,
    const float* __restrict__ v, f16* __restrict__ dq, f16* __restrict__ dk,
    f16* __restrict__ dv) {
  const float* src = blockIdx.z == 0 ? q : blockIdx.z == 1 ? k : v;
  f16* dst = blockIdx.z == 0 ? dq : blockIdx.z == 1 ? dk : dv;
  int i = (blockIdx.x * 256 + threadIdx.x) * 4;
  float4 f = *(const float4*)(src + i);
  f16x4 o = { (f16)f.x, (f16)f.y, (f16)f.z, (f16)f.w };
  *(f16x4*)(dst + i) = o;
}

__global__ __launch_bounds__(256) void tconv2(
    const float* __restrict__ s0, const float* __restrict__ s1,
    f16* __restrict__ d0, f16* __restrict__ d1, int R, int C, int half) {
  int z = blockIdx.z;
  const float* src; f16* dst;
  if (z < half) { src = s0 + (size_t)z * R * C; dst = d0 + (size_t)z * R * C; }
  else { src = s1 + (size_t)(z - half) * R * C; dst = d1 + (size_t)(z - half) * R * C; }
  const int c0 = blockIdx.x * 64, r0 = blockIdx.y * 64;
  __shared__ f16 t[64][72];
  const int tid = threadIdx.x;
#pragma unroll
  for (int i = 0; i < 4; i++) {
    int chunk = tid + i * 256;
    int row = chunk >> 4, c4 = chunk & 15;
    float4 f = *(const float4*)&src[(size_t)(r0 + row) * C + c0 + c4 * 4];
    f16x4 h = { (f16)f.x, (f16)f.y, (f16)f.z, (f16)f.w };
    *(f16x4*)&t[row][c4 * 4] = h;
  }
  __syncthreads();
  const int cc = tid >> 2, q = tid & 3;
  f16 tmp[16];
#pragma unroll
  for (int j = 0; j < 16; j++) tmp[j] = t[q * 16 + j][cc];
  *(f16x8*)&dst[(size_t)(c0 + cc) * R + r0 + q * 16] = *(f16x8*)&tmp[0];
  *(f16x8*)&dst[(size_t)(c0 + cc) * R + r0 + q * 16 + 8] = *(f16x8*)&tmp[8];
}

// ---------------- shared GEMM core: 128x128 tile, BK=64, 4 waves ----------------

__device__ __forceinline__ void gemm_core(
    const f16* __restrict__ A, const f16* __restrict__ Bt, int K, int Kend,
    int row0, int col0, f16* la, f16* lb, int tid, f32x4 (&acc)[4][4]) {
  const int lane = tid & 63;
  const int wr = (tid >> 6) >> 1, wc = (tid >> 6) & 1;
  for (int k0 = 0; k0 < Kend; k0 += 64) {
    __syncthreads();
    stage_swz(A + (size_t)row0 * K + k0, K, la, 1024, tid);
    stage_swz(Bt + (size_t)col0 * K + k0, K, lb, 1024, tid);
    __syncthreads();
#pragma unroll
    for (int ks = 0; ks < 2; ks++) {
      f16x8 af[4], bfr[4];
#pragma unroll
      for (int mi = 0; mi < 4; mi++)
        af[mi] = lds_frag(la, wr * 64 + mi * 16 + (lane & 15), ks * 4 + (lane >> 4));
#pragma unroll
      for (int ni = 0; ni < 4; ni++)
        bfr[ni] = lds_frag(lb, wc * 64 + ni * 16 + (lane & 15), ks * 4 + (lane >> 4));
#pragma unroll
      for (int mi = 0; mi < 4; mi++)
#pragma unroll
        for (int ni = 0; ni < 4; ni++)
          acc[mi][ni] = mfma16(af[mi], bfr[ni], acc[mi][ni]);
    }
  }
}

// ---------------- projection GEMM (q & k batched via z) ----------------

__global__ __launch_bounds__(256) void proj_gemm(
    const f16* __restrict__ A0, const f16* __restrict__ A1,
    const f16* __restrict__ Bt0, const f16* __restrict__ Bt1,
    const float* __restrict__ bias0, const float* __restrict__ bias1,
    f16* __restrict__ C0, f16* __restrict__ C1) {
  const int which = blockIdx.z;
  const f16* A = which ? A1 : A0;
  const f16* Bt = which ? Bt1 : Bt0;
  const float* bias = which ? bias1 : bias0;
  f16* C = which ? C1 : C0;
  __shared__ alignas(16) f16 la[128 * 64];
  __shared__ alignas(16) f16 lb[128 * 64];
  const int tid = threadIdx.x, lane = tid & 63;
  const int wr = (tid >> 6) >> 1, wc = (tid >> 6) & 1;
  const int row0 = blockIdx.x * 128, col0 = blockIdx.y * 128;
  f32x4 acc[4][4];
#pragma unroll
  for (int i = 0; i < 4; i++)
#pragma unroll
    for (int j = 0; j < 4; j++) acc[i][j] = (f32x4){0.f, 0.f, 0.f, 0.f};
  gemm_core(A, Bt, HID, HID, row0, col0, la, lb, tid, acc);
#pragma unroll
  for (int mi = 0; mi < 4; mi++)
#pragma unroll
    for (int ni = 0; ni < 4; ni++)
#pragma unroll
      for (int r = 0; r < 4; r++) {
        int m = row0 + wr * 64 + mi * 16 + ((lane >> 4) << 2) + r;
        int j = col0 + wc * 64 + ni * 16 + (lane & 15);
        float val = acc[mi][ni][r] + bias[j];
        int bb = m >> 10, s = m & 1023, hn = j >> 6, d = j & 63;
        C[(((size_t)hn * BATCH + bb) * SEQ + s) * DHEAD + d] = (f16)val;
      }
}

// ---------------- vv GEMM: vvT[b][v][t] = WvT x v^T + bv[row] ----------------

__global__ __launch_bounds__(256) void vv_gemm(
    const f16* __restrict__ A, const f16* __restrict__ Bt,
    const float* __restrict__ bias, f16* __restrict__ C) {
  __shared__ alignas(16) f16 la[128 * 64];
  __shared__ alignas(16) f16 lb[128 * 64];
  const int tid = threadIdx.x, lane = tid & 63;
  const int wr = (tid >> 6) >> 1, wc = (tid >> 6) & 1;
  const int row0 = blockIdx.x * 128, col0 = blockIdx.y * 128;
  f32x4 acc[4][4];
#pragma unroll
  for (int i = 0; i < 4; i++)
#pragma unroll
    for (int j = 0; j < 4; j++) acc[i][j] = (f32x4){0.f, 0.f, 0.f, 0.f};
  gemm_core(A, Bt, HID, HID, row0, col0, la, lb, tid, acc);
#pragma unroll
  for (int mi = 0; mi < 4; mi++)
#pragma unroll
    for (int ni = 0; ni < 4; ni++)
#pragma unroll
      for (int r = 0; r < 4; r++) {
        int m = row0 + wr * 64 + mi * 16 + ((lane >> 4) << 2) + r;
        int j = col0 + wc * 64 + ni * 16 + (lane & 15);
        float val = acc[mi][ni][r] + bias[m];
        int bb = j >> 10, t = j & 1023;
        C[((size_t)bb * SEQ + m) * SEQ + t] = (f16)val;
      }
}

// ---------------- attention pass 1: LDS-free row sums, group-pipelined ------
// flat grid 2048 XCD-swizzled; 4 waves x 16 rows; groups of 4 k-tiles
// (8 loads) double-buffered in registers: load g+1 while computing g.

__global__ __launch_bounds__(256) void attn_stats(
    const f16* __restrict__ QH, const f16* __restrict__ KH,
    float* __restrict__ madj_ws) {
  const int flat = blockIdx.x;
  const int wg = (flat & 7) * 256 + (flat >> 3);   // XCD chunk swizzle
  const int sb = wg & 15, b = (wg >> 4) & 7, n = wg >> 7;
  const int s0 = sb * 64;
  const f16* qh = QH + ((size_t)n * BATCH + b) * SEQ * DHEAD;
  const f16* kh = KH + ((size_t)n * BATCH + b) * SEQ * DHEAD;

  const int tid = threadIdx.x, lane = tid & 63, wave = tid >> 6;
  const int qrow = s0 + wave * 16 + (lane & 15);
  const int ch = (lane >> 4) << 3;

  f16x8 aq0 = *(const f16x8*)&qh[(size_t)qrow * 64 + ch];
  f16x8 aq1 = *(const f16x8*)&qh[(size_t)qrow * 64 + 32 + ch];

  const float sl2e = 0.125f * 1.44269504088896f;
  float l_p[4] = {0.f, 0.f, 0.f, 0.f};
  const int srow = s0 + wave * 16 + ((lane >> 4) << 2);
  const int nf = (s0 >> 4) + wave;   // diagonal tile index
  const int ntiles = nf + 1;
  const int ngr = (ntiles + 3) >> 2;

  const f16* kp = kh + (size_t)(lane & 15) * 64 + ch;

  f16x8 A0[4], A1[4], B0[4], B1[4];

  auto loadg = [&](int g, f16x8 (&X0)[4], f16x8 (&X1)[4]) {
    int tb = g << 2;
#pragma unroll
    for (int j = 0; j < 4; j++) {
      int t = tb + j; t = t > nf ? nf : t;
      const f16* p = kp + (size_t)t * 1024;
      X0[j] = *(const f16x8*)p;
      X1[j] = *(const f16x8*)(p + 32);
    }
  };
  auto compg = [&](int g, f16x8 (&X0)[4], f16x8 (&X1)[4]) {
    int tb = g << 2;
#pragma unroll
    for (int j = 0; j < 4; j++) {
      int t = tb + j;
      if (t < ntiles) {
        f32x4 c = (f32x4){0.f, 0.f, 0.f, 0.f};
        c = mfma16(aq0, X0[j], c);
        c = mfma16(aq1, X1[j], c);
        if (t == nf) {
          int tg = (t << 4) + (lane & 15);
#pragma unroll
          for (int r = 0; r < 4; r++)
            l_p[r] += (tg <= srow + r) ? exp2f(c[r] * sl2e) : 0.f;
        } else {
#pragma unroll
          for (int r = 0; r < 4; r++) l_p[r] += exp2f(c[r] * sl2e);
        }
      }
    }
  };

  loadg(0, A0, A1);
  int g = 0;
  while (true) {
    if (g + 1 < ngr) loadg(g + 1, B0, B1);
    compg(g, A0, A1);
    if (++g >= ngr) break;
    if (g + 1 < ngr) loadg(g + 1, A0, A1);
    compg(g, B0, B1);
    if (++g >= ngr) break;
  }

#pragma unroll
  for (int r = 0; r < 4; r++) {
    float l = l_p[r];
#pragma unroll
    for (int off = 1; off < 16; off <<= 1) l += __shfl_xor(l, off);
    if ((lane & 15) == 0) {
      size_t base = ((size_t)n * BATCH + b) * SEQ;
      madj_ws[base + srow + r] = -__log2f(l) - 4.0f;  // folds 1/l and /16
    }
  }
}

// ---------------- attention pass 2: LDS-free pbar, cross-head pipeline ------
// flat grid 1152 XCD-swizzled -> (sb,tcid,b,g). Stream of 16 groups
// (8 heads x 2 half-chunks of 4 tiles); K group g+1 and next head's Q/madj
// prefetched while computing group g. Edge blocks: tc<ntc guard + diag mask.

__global__ __launch_bounds__(256) void attn_pbar(
    const f16* __restrict__ QH, const f16* __restrict__ KH,
    const float* __restrict__ madj_ws, f16* __restrict__ pp) {
  const int flat = blockIdx.x;
  const int wg = (flat & 7) * 144 + (flat >> 3);   // XCD chunk swizzle (1152/8)
  int f = wg % 72, sb = 0, tcid = 0;
  const int y = wg / 72;
  for (int s = 15; s >= 0; --s) {
    int c = (s >> 1) + 1;
    if (f < c) { sb = s; tcid = f; break; }
    f -= c;
  }
  const int s0 = sb * 64, t0 = tcid * 128;
  const int b = y >> 1, gg = y & 1;
  const int n0 = gg * 8;

  const int tid = threadIdx.x, lane = tid & 63, wave = tid >> 6;
  const float sl2e = 0.125f * 1.44269504088896f;
  const int ch = (lane >> 4) << 3;
  const int qrow = s0 + wave * 16 + (lane & 15);
  const int srow = s0 + wave * 16 + ((lane >> 4) << 2);
  const int wmin = s0 + wave * 16;
  int ntc = ((wmin + 15 - t0) >> 4) + 1;
  ntc = ntc < 0 ? 0 : (ntc > 8 ? 8 : ntc);
  const bool edge = (t0 + 127) > s0;   // wave-uniform per block... per wave use wmin

  const size_t HS = (size_t)BATCH * SEQ * DHEAD;
  const f16* qbase = QH + (size_t)b * SEQ * DHEAD + (size_t)qrow * 64 + ch;
  const f16* kbase = KH + (size_t)b * SEQ * DHEAD +
                     (size_t)(t0 + (lane & 15)) * 64 + ch;
  const float* mabase = madj_ws + (size_t)b * SEQ + srow;
  const size_t MHS = (size_t)BATCH * SEQ;

  float pacc[8][4];
#pragma unroll
  for (int tc = 0; tc < 8; tc++)
#pragma unroll
    for (int r = 0; r < 4; r++) pacc[tc][r] = 0.f;

  f16x8 KA0[4], KA1[4], KB0[4], KB1[4];
  f16x8 aqC0, aqC1, aqN0, aqN1;
  float4 madjC, madjN;

  auto loadk = [&](int nn, int hf, f16x8 (&X0)[4], f16x8 (&X1)[4]) {
    const f16* p = kbase + (size_t)(n0 + nn) * HS + (size_t)hf * 64 * 64;
#pragma unroll
    for (int j = 0; j < 4; j++) {
      X0[j] = *(const f16x8*)(p + (size_t)j * 1024);
      X1[j] = *(const f16x8*)(p + (size_t)j * 1024 + 32);
    }
  };
  auto loadq = [&](int nn, f16x8& q0, f16x8& q1, float4& ma) {
    const f16* qp = qbase + (size_t)(n0 + nn) * HS;
    q0 = *(const f16x8*)qp;
    q1 = *(const f16x8*)(qp + 32);
    ma = *(const float4*)(mabase + (size_t)(n0 + nn) * MHS);
  };
  auto compk = [&](int hf, f16x8 (&X0)[4], f16x8 (&X1)[4]) {
#pragma unroll
    for (int j = 0; j < 4; j++) {
      int tc = hf * 4 + j;
      if (tc < ntc) {
        f32x4 c = (f32x4){0.f, 0.f, 0.f, 0.f};
        c = mfma16(aqC0, X0[j], c);
        c = mfma16(aqC1, X1[j], c);
        float ma4[4] = {madjC.x, madjC.y, madjC.z, madjC.w};
        bool msk = edge && ((t0 + tc * 16 + 15) > wmin);
        int tg = t0 + tc * 16 + (lane & 15);
#pragma unroll
        for (int r = 0; r < 4; r++) {
          float p2 = exp2f(fmaf(c[r], sl2e, ma4[r]));
          if (msk) p2 = (tg <= srow + r) ? p2 : 0.f;
          pacc[tc][r] += p2;
        }
      }
    }
  };

  loadq(0, aqC0, aqC1, madjC);
  loadk(0, 0, KA0, KA1);
#pragma unroll 1
  for (int gi = 0; gi < 16; gi += 2) {
    int nn = gi >> 1;
    if (gi + 1 < 16) loadk(nn, 1, KB0, KB1);
    if (gi + 2 < 16) loadq(nn + 1, aqN0, aqN1, madjN);
    compk(0, KA0, KA1);
    if (gi + 2 < 16) loadk(nn + 1, 0, KA0, KA1);
    compk(1, KB0, KB1);
    aqC0 = aqN0; aqC1 = aqN1; madjC = madjN;
  }

  f16* out = pp + ((size_t)gg * BATCH + b) * SEQ * SEQ;
#pragma unroll
  for (int tc = 0; tc < 8; tc++) {
    int tg = t0 + tc * 16 + (lane & 15);
#pragma unroll
    for (int r = 0; r < 4; r++)
      out[(size_t)(srow + r) * SEQ + tg] = (f16)pacc[tc][r];
  }
}

// ---------------- PV: out[b] = (pp0[b] + pp1[b]) @ vv[b], causal K-limit ----

__global__ __launch_bounds__(256) void pv_gemm(
    const f16* __restrict__ pp, const f16* __restrict__ vvT,
    float* __restrict__ out) {
  const int b = blockIdx.z;
  const size_t GS = (size_t)BATCH * SEQ * SEQ;
  const f16* A0 = pp + (size_t)b * SEQ * SEQ;
  const f16* A1 = pp + GS + (size_t)b * SEQ * SEQ;
  const f16* Bt = vvT + (size_t)b * SEQ * SEQ;
  __shared__ alignas(16) f16 la0[128 * 64];
  __shared__ alignas(16) f16 la1[128 * 64];
  __shared__ alignas(16) f16 lb[128 * 64];
  const int tid = threadIdx.x, lane = tid & 63;
  const int wr = (tid >> 6) >> 1, wc = (tid >> 6) & 1;
  const int row0 = blockIdx.x * 128, col0 = blockIdx.y * 128;
  const int Kend = (row0 + 128 < SEQ) ? row0 + 128 : SEQ;

  f32x4 acc[4][4];
#pragma unroll
  for (int i = 0; i < 4; i++)
#pragma unroll
    for (int j = 0; j < 4; j++) acc[i][j] = (f32x4){0.f, 0.f, 0.f, 0.f};

  for (int k0 = 0; k0 < Kend; k0 += 64) {
    __syncthreads();
    stage_swz(A0 + (size_t)row0 * SEQ + k0, SEQ, la0, 1024, tid);
    stage_swz(A1 + (size_t)row0 * SEQ + k0, SEQ, la1, 1024, tid);
    stage_swz(Bt + (size_t)col0 * SEQ + k0, SEQ, lb, 1024, tid);
    __syncthreads();
#pragma unroll
    for (int ks = 0; ks < 2; ks++) {
      f16x8 a0[4], a1[4], bfr[4];
#pragma unroll
      for (int mi = 0; mi < 4; mi++) {
        a0[mi] = lds_frag(la0, wr * 64 + mi * 16 + (lane & 15), ks * 4 + (lane >> 4));
        a1[mi] = lds_frag(la1, wr * 64 + mi * 16 + (lane & 15), ks * 4 + (lane >> 4));
      }
#pragma unroll
      for (int ni = 0; ni < 4; ni++)
        bfr[ni] = lds_frag(lb, wc * 64 + ni * 16 + (lane & 15), ks * 4 + (lane >> 4));
#pragma unroll
      for (int mi = 0; mi < 4; mi++)
#pragma unroll
        for (int ni = 0; ni < 4; ni++) {
          acc[mi][ni] = mfma16(a0[mi], bfr[ni], acc[mi][ni]);
          acc[mi][ni] = mfma16(a1[mi], bfr[ni], acc[mi][ni]);
        }
    }
  }

#pragma unroll
  for (int mi = 0; mi < 4; mi++)
#pragma unroll
    for (int ni = 0; ni < 4; ni++)
#pragma unroll
      for (int r = 0; r < 4; r++) {
        int m = row0 + wr * 64 + mi * 16 + ((lane >> 4) << 2) + r;
        int j = col0 + wc * 64 + ni * 16 + (lane & 15);
        out[(size_t)b * SEQ * SEQ + (size_t)m * SEQ + j] = acc[mi][ni][r];
      }
}

// ---------------- launcher ----------------

extern "C" void kernel_launch(void* const* d_in, const int* in_sizes, int n_in,
                              void* d_out, int out_size, void* d_ws, size_t ws_size,
                              hipStream_t stream) {
  (void)in_sizes; (void)n_in; (void)out_size; (void)ws_size;
  const float* q  = (const float*)d_in[0];
  const float* k  = (const float*)d_in[1];
  const float* v  = (const float*)d_in[2];
  const float* Wq = (const float*)d_in[3];
  const float* bq = (const float*)d_in[4];
  const float* Wk = (const float*)d_in[5];
  const float* bk = (const float*)d_in[6];
  const float* Wv = (const float*)d_in[7];
  const float* bv = (const float*)d_in[8];
  float* out = (float*)d_out;

  const size_t EL  = (size_t)BATCH * SEQ * HID;      // 8388608
  const size_t WEL = (size_t)NHEAD * HID * DHEAD;    // 1048576

  char* ws = (char*)d_ws;
  f16* qbf = (f16*)ws;  ws += EL * 2;
  f16* kbf = (f16*)ws;  ws += EL * 2;
  f16* vbf = (f16*)ws;  ws += EL * 2;
  f16* WqT = (f16*)ws;  ws += WEL * 2;
  f16* WkT = (f16*)ws;  ws += WEL * 2;
  f16* WvT = (f16*)ws;  ws += WEL * 2;
  f16* QHb = (f16*)ws;  ws += EL * 2;   // [n][b][s][d]
  f16* KHb = (f16*)ws;  ws += EL * 2;   // [n][b][t][d]
  f16* vvT = (f16*)ws;  ws += EL * 2;   // [b][v][t]
  float* madj_ws = (float*)ws; ws += (size_t)NHEAD * BATCH * SEQ * 4;
  // pp[2][b][s][t] f16 overlays qbf+kbf (dead after proj GEMMs)
  f16* pp = qbf;

  conv3<<<dim3(8192, 1, 3), 256, 0, stream>>>(q, k, v, qbf, kbf, vbf);
  tconv2<<<dim3(1, 16, 32), 256, 0, stream>>>(Wq, Wk, WqT, WkT, 1024, 64, 16);
  tconv2<<<dim3(16, 16, 1), 256, 0, stream>>>(Wv, Wv, WvT, WvT, 1024, 1024, 1);

  proj_gemm<<<dim3(64, 8, 2), 256, 0, stream>>>(qbf, kbf, WqT, WkT, bq, bk,
                                                QHb, KHb);
  vv_gemm<<<dim3(8, 64, 1), 256, 0, stream>>>(WvT, vbf, bv, vvT);

  attn_stats<<<dim3(2048, 1, 1), 256, 0, stream>>>(QHb, KHb, madj_ws);
  attn_pbar<<<dim3(1152, 1, 1), 256, 0, stream>>>(QHb, KHb, madj_ws, pp);
  pv_gemm<<<dim3(8, 8, 8), 256, 0, stream>>>(pp, vvT, out);
}

// Round 9
// 240.739 us; speedup vs baseline: 1.4060x; 1.3043x over previous
//
#include <hip/hip_runtime.h>

// InterpretableMultiHeadAttention: B=8,S=1024,H=1024,NH=16,D=64,V=1024
// out = (mean_n softmax(causal(qh_n kh_n^T / 8))) @ (v Wv + bv)
// Round 9: stats & pbar restructured — wave covers all 64 rows (aq[4][2]) and
// strides K-tiles (K read once per block, 8 MFMA per 2 loads); stats LPT
// dispatch (heaviest first, per-(n,b) XCD affinity) + 1KB LDS combine.

#define NHEAD 16
#define BATCH 8
#define SEQ   1024
#define HID   1024
#define DHEAD 64

typedef _Float16 f16;
typedef _Float16 f16x4 __attribute__((ext_vector_type(4)));
typedef _Float16 f16x8 __attribute__((ext_vector_type(8)));
typedef float    f32x4 __attribute__((ext_vector_type(4)));

__device__ __forceinline__ f32x4 mfma16(f16x8 a, f16x8 b, f32x4 c) {
  return __builtin_amdgcn_mfma_f32_16x16x32_f16(a, b, c, 0, 0, 0);
}

__device__ __forceinline__ void gload16(const f16* g, f16* l) {
  __builtin_amdgcn_global_load_lds(
      (const __attribute__((address_space(1))) void*)g,
      (__attribute__((address_space(3))) void*)l, 16, 0, 0);
}

// GEMM staging (verified conflict-free).
__device__ __forceinline__ void stage_swz(const f16* __restrict__ g, int ldg,
                                          f16* lds, int nch, int tid) {
  for (int idx = tid; idx < nch; idx += 256) {
    int row = idx >> 3, c16 = idx & 7;
    int sc = c16 ^ (row & 7);
    gload16(g + (size_t)row * ldg + sc * 8, lds + (size_t)(idx & ~63) * 8);
  }
}

__device__ __forceinline__ f16x8 lds_frag(const f16* lds, int row, int c16) {
  int sc = c16 ^ (row & 7);
  return *(const f16x8*)&lds[row * 64 + sc * 8];
}

// ---------------- conversions ----------------

__global__ __launch_bounds__(256) void conv3(
    const float* __restrict__ q, const float* __restrict__ k,
    const float* __restrict__ v, f16* __restrict__ dq, f16* __restrict__ dk,
    f16* __restrict__ dv) {
  const float* src = blockIdx.z == 0 ? q : blockIdx.z == 1 ? k : v;
  f16* dst = blockIdx.z == 0 ? dq : blockIdx.z == 1 ? dk : dv;
  int i = (blockIdx.x * 256 + threadIdx.x) * 4;
  float4 f = *(const float4*)(src + i);
  f16x4 o = { (f16)f.x, (f16)f.y, (f16)f.z, (f16)f.w };
  *(f16x4*)(dst + i) = o;
}

__global__ __launch_bounds__(256) void tconv2(
    const float* __restrict__ s0, const float* __restrict__ s1,
    f16* __restrict__ d0, f16* __restrict__ d1, int R, int C, int half) {
  int z = blockIdx.z;
  const float* src; f16* dst;
  if (z < half) { src = s0 + (size_t)z * R * C; dst = d0 + (size_t)z * R * C; }
  else { src = s1 + (size_t)(z - half) * R * C; dst = d1 + (size_t)(z - half) * R * C; }
  const int c0 = blockIdx.x * 64, r0 = blockIdx.y * 64;
  __shared__ f16 t[64][72];
  const int tid = threadIdx.x;
#pragma unroll
  for (int i = 0; i < 4; i++) {
    int chunk = tid + i * 256;
    int row = chunk >> 4, c4 = chunk & 15;
    float4 f = *(const float4*)&src[(size_t)(r0 + row) * C + c0 + c4 * 4];
    f16x4 h = { (f16)f.x, (f16)f.y, (f16)f.z, (f16)f.w };
    *(f16x4*)&t[row][c4 * 4] = h;
  }
  __syncthreads();
  const int cc = tid >> 2, q = tid & 3;
  f16 tmp[16];
#pragma unroll
  for (int j = 0; j < 16; j++) tmp[j] = t[q * 16 + j][cc];
  *(f16x8*)&dst[(size_t)(c0 + cc) * R + r0 + q * 16] = *(f16x8*)&tmp[0];
  *(f16x8*)&dst[(size_t)(c0 + cc) * R + r0 + q * 16 + 8] = *(f16x8*)&tmp[8];
}

// ---------------- shared GEMM core: 128x128 tile, BK=64, 4 waves ----------------

__device__ __forceinline__ void gemm_core(
    const f16* __restrict__ A, const f16* __restrict__ Bt, int K, int Kend,
    int row0, int col0, f16* la, f16* lb, int tid, f32x4 (&acc)[4][4]) {
  const int lane = tid & 63;
  const int wr = (tid >> 6) >> 1, wc = (tid >> 6) & 1;
  for (int k0 = 0; k0 < Kend; k0 += 64) {
    __syncthreads();
    stage_swz(A + (size_t)row0 * K + k0, K, la, 1024, tid);
    stage_swz(Bt + (size_t)col0 * K + k0, K, lb, 1024, tid);
    __syncthreads();
#pragma unroll
    for (int ks = 0; ks < 2; ks++) {
      f16x8 af[4], bfr[4];
#pragma unroll
      for (int mi = 0; mi < 4; mi++)
        af[mi] = lds_frag(la, wr * 64 + mi * 16 + (lane & 15), ks * 4 + (lane >> 4));
#pragma unroll
      for (int ni = 0; ni < 4; ni++)
        bfr[ni] = lds_frag(lb, wc * 64 + ni * 16 + (lane & 15), ks * 4 + (lane >> 4));
#pragma unroll
      for (int mi = 0; mi < 4; mi++)
#pragma unroll
        for (int ni = 0; ni < 4; ni++)
          acc[mi][ni] = mfma16(af[mi], bfr[ni], acc[mi][ni]);
    }
  }
}

// ---------------- projection GEMM (q & k batched via z) ----------------

__global__ __launch_bounds__(256) void proj_gemm(
    const f16* __restrict__ A0, const f16* __restrict__ A1,
    const f16* __restrict__ Bt0, const f16* __restrict__ Bt1,
    const float* __restrict__ bias0, const float* __restrict__ bias1,
    f16* __restrict__ C0, f16* __restrict__ C1) {
  const int which = blockIdx.z;
  const f16* A = which ? A1 : A0;
  const f16* Bt = which ? Bt1 : Bt0;
  const float* bias = which ? bias1 : bias0;
  f16* C = which ? C1 : C0;
  __shared__ alignas(16) f16 la[128 * 64];
  __shared__ alignas(16) f16 lb[128 * 64];
  const int tid = threadIdx.x, lane = tid & 63;
  const int wr = (tid >> 6) >> 1, wc = (tid >> 6) & 1;
  const int row0 = blockIdx.x * 128, col0 = blockIdx.y * 128;
  f32x4 acc[4][4];
#pragma unroll
  for (int i = 0; i < 4; i++)
#pragma unroll
    for (int j = 0; j < 4; j++) acc[i][j] = (f32x4){0.f, 0.f, 0.f, 0.f};
  gemm_core(A, Bt, HID, HID, row0, col0, la, lb, tid, acc);
#pragma unroll
  for (int mi = 0; mi < 4; mi++)
#pragma unroll
    for (int ni = 0; ni < 4; ni++)
#pragma unroll
      for (int r = 0; r < 4; r++) {
        int m = row0 + wr * 64 + mi * 16 + ((lane >> 4) << 2) + r;
        int j = col0 + wc * 64 + ni * 16 + (lane & 15);
        float val = acc[mi][ni][r] + bias[j];
        int bb = m >> 10, s = m & 1023, hn = j >> 6, d = j & 63;
        C[(((size_t)hn * BATCH + bb) * SEQ + s) * DHEAD + d] = (f16)val;
      }
}

// ---------------- vv GEMM: vvT[b][v][t] = WvT x v^T + bv[row] ----------------

__global__ __launch_bounds__(256) void vv_gemm(
    const f16* __restrict__ A, const f16* __restrict__ Bt,
    const float* __restrict__ bias, f16* __restrict__ C) {
  __shared__ alignas(16) f16 la[128 * 64];
  __shared__ alignas(16) f16 lb[128 * 64];
  const int tid = threadIdx.x, lane = tid & 63;
  const int wr = (tid >> 6) >> 1, wc = (tid >> 6) & 1;
  const int row0 = blockIdx.x * 128, col0 = blockIdx.y * 128;
  f32x4 acc[4][4];
#pragma unroll
  for (int i = 0; i < 4; i++)
#pragma unroll
    for (int j = 0; j < 4; j++) acc[i][j] = (f32x4){0.f, 0.f, 0.f, 0.f};
  gemm_core(A, Bt, HID, HID, row0, col0, la, lb, tid, acc);
#pragma unroll
  for (int mi = 0; mi < 4; mi++)
#pragma unroll
    for (int ni = 0; ni < 4; ni++)
#pragma unroll
      for (int r = 0; r < 4; r++) {
        int m = row0 + wr * 64 + mi * 16 + ((lane >> 4) << 2) + r;
        int j = col0 + wc * 64 + ni * 16 + (lane & 15);
        float val = acc[mi][ni][r] + bias[m];
        int bb = j >> 10, t = j & 1023;
        C[((size_t)bb * SEQ + m) * SEQ + t] = (f16)val;
      }
}

// ---------------- attention pass 1: row sums, 64 rows/wave, K-split ----------
// flat = (15-sb)*128 + n*8 + b  (heaviest first; per-(n,b) XCD affinity).
// Wave w computes tiles j = w, w+4, ... (K read once per block). 8 MFMA/tile.
// Tiles j >= 4*sb are per-element masked. 1KB LDS cross-wave combine.

__global__ __launch_bounds__(256) void attn_stats(
    const f16* __restrict__ QH, const f16* __restrict__ KH,
    float* __restrict__ madj_ws) {
  const int flat = blockIdx.x;
  const int sb = 15 - (flat >> 7);
  const int nb = flat & 127;
  const int n = nb >> 3, b = nb & 7;
  const int s0 = sb * 64;
  const f16* qh = QH + ((size_t)n * BATCH + b) * SEQ * DHEAD;
  const f16* kh = KH + ((size_t)n * BATCH + b) * SEQ * DHEAD;

  const int tid = threadIdx.x, lane = tid & 63, wave = tid >> 6;
  const int lr = lane & 15;          // A-row / B-col selector
  const int qg = lane >> 4;          // C row group
  const int ch = qg << 3;            // k-chunk

  f16x8 aq[4][2];
#pragma unroll
  for (int fi = 0; fi < 4; fi++) {
    const f16* qp = qh + (size_t)(s0 + fi * 16 + lr) * 64 + ch;
    aq[fi][0] = *(const f16x8*)qp;
    aq[fi][1] = *(const f16x8*)(qp + 32);
  }

  const float sl2e = 0.125f * 1.44269504088896f;
  float l_p[16];
#pragma unroll
  for (int i = 0; i < 16; i++) l_p[i] = 0.f;

  const int nt = (sb + 1) * 4;   // tiles 0..nt-1; j >= 4sb masked
  const int dstart = sb * 4;
  const int njw = (nt - wave + 3) >> 2;   // this wave's tile count (>=1)
  const f16* kp = kh + (size_t)lr * 64 + ch;

  f16x8 kA0, kA1, kB0, kB1;

#define LDK(jj, X0, X1) { const f16* p_ = kp + (size_t)(jj) * 1024; \
    X0 = *(const f16x8*)p_; X1 = *(const f16x8*)(p_ + 32); }

#define COMP(jj, X0, X1) { \
    f32x4 c_[4]; \
    _Pragma("unroll") for (int fi = 0; fi < 4; fi++) { \
      f32x4 cc = (f32x4){0.f, 0.f, 0.f, 0.f}; \
      cc = mfma16(aq[fi][0], X0, cc); cc = mfma16(aq[fi][1], X1, cc); \
      c_[fi] = cc; } \
    if ((jj) < dstart) { \
      _Pragma("unroll") for (int fi = 0; fi < 4; fi++) \
        _Pragma("unroll") for (int r = 0; r < 4; r++) \
          l_p[fi * 4 + r] += exp2f(c_[fi][r] * sl2e); \
    } else { \
      int tg_ = (jj) * 16 + lr; \
      _Pragma("unroll") for (int fi = 0; fi < 4; fi++) \
        _Pragma("unroll") for (int r = 0; r < 4; r++) { \
          int sg_ = s0 + fi * 16 + qg * 4 + r; \
          l_p[fi * 4 + r] += (tg_ <= sg_) ? exp2f(c_[fi][r] * sl2e) : 0.f; } } }

  LDK(wave, kA0, kA1);
  int idx = 0;
  for (; idx + 2 <= njw; idx += 2) {
    LDK(wave + (idx + 1) * 4, kB0, kB1);
    COMP(wave + idx * 4, kA0, kA1);
    if (idx + 2 < njw) LDK(wave + (idx + 2) * 4, kA0, kA1);
    COMP(wave + (idx + 1) * 4, kB0, kB1);
  }
  if (idx < njw) COMP(wave + idx * 4, kA0, kA1);
#undef LDK
#undef COMP

  __shared__ float lds_l[4][64];
#pragma unroll
  for (int i = 0; i < 16; i++) {
    float l = l_p[i];
    l += __shfl_xor(l, 1); l += __shfl_xor(l, 2);
    l += __shfl_xor(l, 4); l += __shfl_xor(l, 8);
    if (lr == 0) lds_l[wave][(i >> 2) * 16 + qg * 4 + (i & 3)] = l;
  }
  __syncthreads();
  if (tid < 64) {
    float l = lds_l[0][tid] + lds_l[1][tid] + lds_l[2][tid] + lds_l[3][tid];
    madj_ws[((size_t)n * BATCH + b) * SEQ + s0 + tid] = -__log2f(l) - 4.0f;
  }
}

// ---------------- attention pass 2: pbar partials, 64 rows/wave -------------
// flat grid 1152 XCD decode (longest-first). Wave owns tiles {w, w+4} of the
// 8 16-col tiles; K read once per block per head; zero-fill via pacc write.

__global__ __launch_bounds__(256) void attn_pbar(
    const f16* __restrict__ QH, const f16* __restrict__ KH,
    const float* __restrict__ madj_ws, f16* __restrict__ pp) {
  const int flat = blockIdx.x;
  const int wg = (flat & 7) * 144 + (flat >> 3);
  int f = wg % 72, sb = 0, tcid = 0;
  const int y = wg / 72;
  for (int s = 15; s >= 0; --s) {
    int c = (s >> 1) + 1;
    if (f < c) { sb = s; tcid = f; break; }
    f -= c;
  }
  const int s0 = sb * 64, t0 = tcid * 128;
  const int b = y >> 1, gg = y & 1;
  const int n0 = gg * 8;

  const int tid = threadIdx.x, lane = tid & 63, wave = tid >> 6;
  const float sl2e = 0.125f * 1.44269504088896f;
  const int lr = lane & 15, qg = lane >> 4, ch = qg << 3;

  int ntc = ((s0 + 63 - t0) >> 4) + 1;
  ntc = ntc > 8 ? 8 : ntc;                 // >= 4 by construction
  const int j0 = wave, j1 = wave + 4;
  const bool has1 = j1 < ntc;

  const size_t HS = (size_t)BATCH * SEQ * DHEAD;
  const size_t MHS = (size_t)BATCH * SEQ;
  const f16* qbase = QH + (size_t)b * SEQ * DHEAD;
  const f16* kbase = KH + (size_t)b * SEQ * DHEAD;
  const float* mabase = madj_ws + (size_t)b * SEQ;

  float paccA[16], paccB[16];
#pragma unroll
  for (int i = 0; i < 16; i++) { paccA[i] = 0.f; paccB[i] = 0.f; }

  for (int nn = 0; nn < 8; nn++) {
    const int n = n0 + nn;
    const f16* qh = qbase + (size_t)n * HS;
    const f16* kh = kbase + (size_t)n * HS;

    // K tiles first (needed first together with aq)
    f16x8 kA0, kA1, kB0, kB1;
    {
      const f16* p = kh + (size_t)(t0 + j0 * 16 + lr) * 64 + ch;
      kA0 = *(const f16x8*)p; kA1 = *(const f16x8*)(p + 32);
    }
    if (has1) {
      const f16* p = kh + (size_t)(t0 + j1 * 16 + lr) * 64 + ch;
      kB0 = *(const f16x8*)p; kB1 = *(const f16x8*)(p + 32);
    }
    f16x8 aq[4][2];
#pragma unroll
    for (int fi = 0; fi < 4; fi++) {
      const f16* qp = qh + (size_t)(s0 + fi * 16 + lr) * 64 + ch;
      aq[fi][0] = *(const f16x8*)qp;
      aq[fi][1] = *(const f16x8*)(qp + 32);
    }
    float ma[4][4];
#pragma unroll
    for (int fi = 0; fi < 4; fi++) {
      float4 m4 = *(const float4*)&mabase[(size_t)n * MHS + s0 + fi * 16 + qg * 4];
      ma[fi][0] = m4.x; ma[fi][1] = m4.y; ma[fi][2] = m4.z; ma[fi][3] = m4.w;
    }

#define PCOMP(jj, X0, X1, PC) { \
    int tg_ = t0 + (jj) * 16 + lr; \
    _Pragma("unroll") for (int fi = 0; fi < 4; fi++) { \
      f32x4 cc = (f32x4){0.f, 0.f, 0.f, 0.f}; \
      cc = mfma16(aq[fi][0], X0, cc); cc = mfma16(aq[fi][1], X1, cc); \
      _Pragma("unroll") for (int r = 0; r < 4; r++) { \
        int sg_ = s0 + fi * 16 + qg * 4 + r; \
        float p_ = exp2f(fmaf(cc[r], sl2e, ma[fi][r])); \
        PC[fi * 4 + r] += (tg_ <= sg_) ? p_ : 0.f; } } }

    PCOMP(j0, kA0, kA1, paccA);
    if (has1) PCOMP(j1, kB0, kB1, paccB);
#undef PCOMP
  }

  f16* out = pp + ((size_t)gg * BATCH + b) * SEQ * SEQ;
#pragma unroll
  for (int fi = 0; fi < 4; fi++) {
#pragma unroll
    for (int r = 0; r < 4; r++) {
      size_t row = (size_t)(s0 + fi * 16 + qg * 4 + r) * SEQ;
      out[row + t0 + j0 * 16 + lr] = (f16)paccA[fi * 4 + r];
      out[row + t0 + j1 * 16 + lr] = (f16)paccB[fi * 4 + r];  // zeros if !has1
    }
  }
}

// ---------------- PV: out[b] = (pp0[b] + pp1[b]) @ vv[b], causal K-limit ----

__global__ __launch_bounds__(256) void pv_gemm(
    const f16* __restrict__ pp, const f16* __restrict__ vvT,
    float* __restrict__ out) {
  const int b = blockIdx.z;
  const size_t GS = (size_t)BATCH * SEQ * SEQ;
  const f16* A0 = pp + (size_t)b * SEQ * SEQ;
  const f16* A1 = pp + GS + (size_t)b * SEQ * SEQ;
  const f16* Bt = vvT + (size_t)b * SEQ * SEQ;
  __shared__ alignas(16) f16 la0[128 * 64];
  __shared__ alignas(16) f16 la1[128 * 64];
  __shared__ alignas(16) f16 lb[128 * 64];
  const int tid = threadIdx.x, lane = tid & 63;
  const int wr = (tid >> 6) >> 1, wc = (tid >> 6) & 1;
  const int row0 = blockIdx.x * 128, col0 = blockIdx.y * 128;
  const int Kend = (row0 + 128 < SEQ) ? row0 + 128 : SEQ;

  f32x4 acc[4][4];
#pragma unroll
  for (int i = 0; i < 4; i++)
#pragma unroll
    for (int j = 0; j < 4; j++) acc[i][j] = (f32x4){0.f, 0.f, 0.f, 0.f};

  for (int k0 = 0; k0 < Kend; k0 += 64) {
    __syncthreads();
    stage_swz(A0 + (size_t)row0 * SEQ + k0, SEQ, la0, 1024, tid);
    stage_swz(A1 + (size_t)row0 * SEQ + k0, SEQ, la1, 1024, tid);
    stage_swz(Bt + (size_t)col0 * SEQ + k0, SEQ, lb, 1024, tid);
    __syncthreads();
#pragma unroll
    for (int ks = 0; ks < 2; ks++) {
      f16x8 a0[4], a1[4], bfr[4];
#pragma unroll
      for (int mi = 0; mi < 4; mi++) {
        a0[mi] = lds_frag(la0, wr * 64 + mi * 16 + (lane & 15), ks * 4 + (lane >> 4));
        a1[mi] = lds_frag(la1, wr * 64 + mi * 16 + (lane & 15), ks * 4 + (lane >> 4));
      }
#pragma unroll
      for (int ni = 0; ni < 4; ni++)
        bfr[ni] = lds_frag(lb, wc * 64 + ni * 16 + (lane & 15), ks * 4 + (lane >> 4));
#pragma unroll
      for (int mi = 0; mi < 4; mi++)
#pragma unroll
        for (int ni = 0; ni < 4; ni++) {
          acc[mi][ni] = mfma16(a0[mi], bfr[ni], acc[mi][ni]);
          acc[mi][ni] = mfma16(a1[mi], bfr[ni], acc[mi][ni]);
        }
    }
  }

#pragma unroll
  for (int mi = 0; mi < 4; mi++)
#pragma unroll
    for (int ni = 0; ni < 4; ni++)
#pragma unroll
      for (int r = 0; r < 4; r++) {
        int m = row0 + wr * 64 + mi * 16 + ((lane >> 4) << 2) + r;
        int j = col0 + wc * 64 + ni * 16 + (lane & 15);
        out[(size_t)b * SEQ * SEQ + (size_t)m * SEQ + j] = acc[mi][ni][r];
      }
}

// ---------------- launcher ----------------

extern "C" void kernel_launch(void* const* d_in, const int* in_sizes, int n_in,
                              void* d_out, int out_size, void* d_ws, size_t ws_size,
                              hipStream_t stream) {
  (void)in_sizes; (void)n_in; (void)out_size; (void)ws_size;
  const float* q  = (const float*)d_in[0];
  const float* k  = (const float*)d_in[1];
  const float* v  = (const float*)d_in[2];
  const float* Wq = (const float*)d_in[3];
  const float* bq = (const float*)d_in[4];
  const float* Wk = (const float*)d_in[5];
  const float* bk = (const float*)d_in[6];
  const float* Wv = (const float*)d_in[7];
  const float* bv = (const float*)d_in[8];
  float* out = (float*)d_out;

  const size_t EL  = (size_t)BATCH * SEQ * HID;      // 8388608
  const size_t WEL = (size_t)NHEAD * HID * DHEAD;    // 1048576

  char* ws = (char*)d_ws;
  f16* qbf = (f16*)ws;  ws += EL * 2;
  f16* kbf = (f16*)ws;  ws += EL * 2;
  f16* vbf = (f16*)ws;  ws += EL * 2;
  f16* WqT = (f16*)ws;  ws += WEL * 2;
  f16* WkT = (f16*)ws;  ws += WEL * 2;
  f16* WvT = (f16*)ws;  ws += WEL * 2;
  f16* QHb = (f16*)ws;  ws += EL * 2;   // [n][b][s][d]
  f16* KHb = (f16*)ws;  ws += EL * 2;   // [n][b][t][d]
  f16* vvT = (f16*)ws;  ws += EL * 2;   // [b][v][t]
  float* madj_ws = (float*)ws; ws += (size_t)NHEAD * BATCH * SEQ * 4;
  // pp[2][b][s][t] f16 overlays qbf+kbf (dead after proj GEMMs)
  f16* pp = qbf;

  conv3<<<dim3(8192, 1, 3), 256, 0, stream>>>(q, k, v, qbf, kbf, vbf);
  tconv2<<<dim3(1, 16, 32), 256, 0, stream>>>(Wq, Wk, WqT, WkT, 1024, 64, 16);
  tconv2<<<dim3(16, 16, 1), 256, 0, stream>>>(Wv, Wv, WvT, WvT, 1024, 1024, 1);

  proj_gemm<<<dim3(64, 8, 2), 256, 0, stream>>>(qbf, kbf, WqT, WkT, bq, bk,
                                                QHb, KHb);
  vv_gemm<<<dim3(8, 64, 1), 256, 0, stream>>>(WvT, vbf, bv, vvT);

  attn_stats<<<dim3(2048, 1, 1), 256, 0, stream>>>(QHb, KHb, madj_ws);
  attn_pbar<<<dim3(1152, 1, 1), 256, 0, stream>>>(QHb, KHb, madj_ws, pp);
  pv_gemm<<<dim3(8, 8, 8), 256, 0, stream>>>(pp, vvT, out);
}